// Round 1
// baseline (995.659 us; speedup 1.0000x reference)
//
#include <hip/hip_runtime.h>
#include <math.h>

#define BB 4
#define HH 8
#define LL 2048
#define DD 64
#define SK 40            // sample_k == u == 40 for L=2048, FACTOR=5
#define BH (BB*HH)       // 32
#define NC 8             // key-chunks per (bh,u) in attn

__device__ __forceinline__ unsigned ordu(float v) {
    unsigned u = __float_as_uint(v);
    return (u & 0x80000000u) ? ~u : (u | 0x80000000u);
}

// ---------------------------------------------------------------------------
// Stage 1: blocks [0,1024) compute M; blocks [1024,1536) compute V chunk sums.
__global__ __launch_bounds__(256) void stage1_kernel(
        const float* __restrict__ Q, const float* __restrict__ K,
        const float* __restrict__ V, const int* __restrict__ IDX,
        float* __restrict__ M, float* __restrict__ csum) {
    int tid = threadIdx.x;
    if (blockIdx.x < 1024) {
        // ----- compute_M: 4 lanes/query, 16 queries/wave, 64 queries/block
        int x = blockIdx.x;
        int bhLo = x & 7;
        int r = x >> 3;                   // [0,128)
        int bhHi = r & 3;
        int chunk = r >> 2;               // [0,32)
        int bh = bhHi * 8 + bhLo;
        int qbase = chunk * 64;
        int w = tid >> 6, lane = tid & 63;
        int qw = lane >> 2, c = lane & 3;
        int qi = w * 16 + qw;
        int qpos = qbase + qi;

        __shared__ int sidx[64 * SK];     // 10 KB
        for (int i = tid; i < 64 * SK; i += 256) sidx[i] = IDX[(size_t)qbase * SK + i];

        const float4* Q4 = (const float4*)Q;
        const float4* K4 = (const float4*)K;
        float4 qreg[4];
        #pragma unroll
        for (int j = 0; j < 4; ++j)
            qreg[j] = Q4[((size_t)bh * LL + qpos) * 16 + j * 4 + c];
        __syncthreads();

        size_t kb4 = (size_t)bh * LL * 16;
        float mx = -INFINITY, sm = 0.f;
        #pragma unroll 8
        for (int s = 0; s < SK; ++s) {
            int ks = sidx[qi * SK + s];
            const float4* kr = K4 + kb4 + (size_t)ks * 16;
            float p = 0.f;
            #pragma unroll
            for (int j = 0; j < 4; ++j) {
                float4 kv = kr[j * 4 + c];
                p += qreg[j].x * kv.x + qreg[j].y * kv.y + qreg[j].z * kv.z + qreg[j].w * kv.w;
            }
            p += __shfl_xor(p, 1, 64);
            p += __shfl_xor(p, 2, 64);
            mx = fmaxf(mx, p);
            sm += p;
        }
        if (c == 0) M[(size_t)bh * LL + qpos] = mx - sm * (1.0f / (float)LL);
    } else {
        // ----- vsum: per-(bh,chunk-of-128) column sums of V
        int x = blockIdx.x - 1024;        // [0,512)
        int bhLo = x & 7, r = x >> 3;
        int bhHi = r & 3, c = r >> 2;     // c in [0,16)
        int bh = bhHi * 8 + bhLo;
        int d = tid & 63, sg = tid >> 6;
        size_t base = (size_t)bh * LL * DD;
        int row0 = c * 128 + sg * 32;
        float s = 0.f;
        for (int j = 0; j < 32; ++j) s += V[base + (size_t)(row0 + j) * DD + d];
        __shared__ float part[4][DD];
        part[sg][d] = s;
        __syncthreads();
        if (sg == 0)
            csum[((size_t)bh * 16 + c) * DD + d] = part[0][d] + part[1][d] + part[2][d] + part[3][d];
    }
}

// ---------------------------------------------------------------------------
// Stage 2: blocks [0,512) cumsum V -> out; blocks [512,544) radix top-40 of M.
__global__ __launch_bounds__(256) void stage2_kernel(
        const float* __restrict__ V, const float* __restrict__ csum,
        const float* __restrict__ M, float* __restrict__ out,
        int* __restrict__ topk, int* __restrict__ cnt) {
    int tid = threadIdx.x;
    if (blockIdx.x < 512) {
        // ----- cumsum
        int x = blockIdx.x;
        int bhLo = x & 7, r = x >> 3;
        int bhHi = r & 3, c = r >> 2;
        int bh = bhHi * 8 + bhLo;
        int d = tid & 63, sg = tid >> 6;
        size_t base = (size_t)bh * LL * DD;
        int row0 = c * 128 + sg * 32;
        float v[32];
        #pragma unroll
        for (int j = 0; j < 32; ++j) v[j] = V[base + (size_t)(row0 + j) * DD + d];
        float s = 0.f;
        #pragma unroll
        for (int j = 0; j < 32; ++j) s += v[j];
        __shared__ float part[4][DD];
        part[sg][d] = s;
        __syncthreads();
        float pre = 0.f;
        for (int cc = 0; cc < c; ++cc) pre += csum[((size_t)bh * 16 + cc) * DD + d];
        for (int ss = 0; ss < sg; ++ss) pre += part[ss][d];
        float acc = pre;
        #pragma unroll
        for (int j = 0; j < 32; ++j) {
            acc += v[j];
            out[base + (size_t)(row0 + j) * DD + d] = acc;
        }
    } else {
        // ----- radix top-40 (8 bits/pass, 4 passes); unordered emission.
        int bh = blockIdx.x - 512;
        if (tid < SK) cnt[bh * SK + tid] = 0;   // reset attn combine counters
        __shared__ unsigned hist[256];
        __shared__ unsigned bc_prefix, bc_need;
        __shared__ unsigned cnt_gt, cnt_eq;
        __shared__ int eqlist[128];

        unsigned v[8];
        #pragma unroll
        for (int j = 0; j < 8; ++j)
            v[j] = ordu(M[(size_t)bh * LL + tid + j * 256]);

        unsigned prefix = 0, need = SK;
        #pragma unroll
        for (int pass = 0; pass < 4; ++pass) {
            const int s = 24 - 8 * pass;
            const unsigned maskHigh = (pass == 0) ? 0u : (0xFFFFFFFFu << (s + 8));
            hist[tid] = 0;
            __syncthreads();
            #pragma unroll
            for (int j = 0; j < 8; ++j)
                if (((v[j] ^ prefix) & maskHigh) == 0)
                    atomicAdd(&hist[(v[j] >> s) & 0xFF], 1u);
            __syncthreads();
            unsigned above = 0;
            for (int b = tid + 1; b < 256; ++b) above += hist[b];
            if (above < need && above + hist[tid] >= need) {
                bc_prefix = prefix | ((unsigned)tid << s);
                bc_need = need - above;
            }
            __syncthreads();
            prefix = bc_prefix;
            need = bc_need;
            __syncthreads();
        }
        unsigned T = prefix;
        if (tid == 0) { cnt_gt = 0; cnt_eq = 0; }
        __syncthreads();
        #pragma unroll
        for (int j = 0; j < 8; ++j) {
            int idx = tid + j * 256;
            if (v[j] > T) { unsigned p = atomicAdd(&cnt_gt, 1u); topk[bh * SK + p] = idx; }
            else if (v[j] == T) { unsigned p = atomicAdd(&cnt_eq, 1u); if (p < 128) eqlist[p] = idx; }
        }
        __syncthreads();
        if (tid == 0) {
            int ne = (int)min(cnt_eq, 128u);
            unsigned base = cnt_gt;       // == SK - need
            for (unsigned r2 = 0; r2 < need; ++r2) {
                int bj = 0, bv = 0x7FFFFFFF;
                for (int j = 0; j < ne; ++j)
                    if (eqlist[j] < bv) { bv = eqlist[j]; bj = j; }
                topk[bh * SK + base + r2] = bv;
                eqlist[bj] = 0x7FFFFFFF;
            }
        }
    }
}

// ---------------------------------------------------------------------------
// Stage 3: flash-style chunked attention. NC chunk-blocks per (bh,u), each
// computes a partial (max, sumexp, weighted-V) over ~nk/NC keys; the
// last-arriving block combines partials and writes out[bh,qpos,:].
__global__ __launch_bounds__(256) void attn_kernel(
        const float* __restrict__ Q, const float* __restrict__ K,
        const float* __restrict__ V, const int* __restrict__ topk,
        float* __restrict__ pm, float* __restrict__ pl,
        float* __restrict__ po, int* __restrict__ cnt,
        float* __restrict__ out) {
    int x = blockIdx.x;               // [0, BH*SK*NC) = 10240
    int bhLo = x & 7;                 // XCD-affinity: same bhLo -> same XCD
    int r = x >> 3;                   // [0, 1280)
    int c = r & 7;                    // chunk index [0,NC)
    r >>= 3;                          // [0, 160)
    int u = r % SK;
    int bhHi = r / SK;                // [0,4)
    int bh = bhHi * 8 + bhLo;
    int g = bh * SK + u;              // group id [0, 1280)
    int tid = threadIdx.x;

    int qpos = topk[g];
    int nk = qpos + 1;
    int cl = (nk + NC - 1) >> 3;      // chunk length (<= 256)
    int k0 = c * cl;
    int len = min(cl, nk - k0);       // may be <= 0 (block-uniform)

    __shared__ float sc[256];
    __shared__ float red[4], red2[4];
    __shared__ float opart[16][16][4];
    __shared__ int lastFlag;

    size_t pbase = (size_t)g * NC + c;

    if (len > 0) {
        int w = tid >> 6, lane = tid & 63;
        int kw = lane >> 2, cc = lane & 3;
        const float4* Q4 = (const float4*)Q;
        const float4* K4 = (const float4*)K;
        const float4* V4 = (const float4*)V;
        float4 qreg[4];
        #pragma unroll
        for (int j = 0; j < 4; ++j)
            qreg[j] = Q4[((size_t)bh * LL + qpos) * 16 + j * 4 + cc];

        // score phase: 4 lanes/key, 64 keys per block-round
        size_t kb4 = (size_t)bh * LL * 16;
        int rounds = (len + 63) >> 6;
        for (int rr = 0; rr < rounds; ++rr) {
            int j = rr * 64 + w * 16 + kw;
            if (j < len) {
                const float4* kr = K4 + kb4 + (size_t)(k0 + j) * 16;
                float p = 0.f;
                #pragma unroll
                for (int jj = 0; jj < 4; ++jj) {
                    float4 kv = kr[jj * 4 + cc];
                    p += qreg[jj].x * kv.x + qreg[jj].y * kv.y + qreg[jj].z * kv.z + qreg[jj].w * kv.w;
                }
                p += __shfl_xor(p, 1, 64);
                p += __shfl_xor(p, 2, 64);
                if (cc == 0) sc[j] = p * 0.125f;   // 1/sqrt(64)
            }
        }
        __syncthreads();

        // chunk max (len <= 256: one element per thread)
        float m = (tid < len) ? sc[tid] : -INFINITY;
        #pragma unroll
        for (int off = 32; off > 0; off >>= 1) m = fmaxf(m, __shfl_xor(m, off, 64));
        if (lane == 0) red[w] = m;
        __syncthreads();
        m = fmaxf(fmaxf(red[0], red[1]), fmaxf(red[2], red[3]));

        // exp + chunk sum
        float e = 0.f;
        if (tid < len) {
            e = expf(sc[tid] - m);
            sc[tid] = e;
        }
        #pragma unroll
        for (int off = 32; off > 0; off >>= 1) e += __shfl_xor(e, off, 64);
        if (lane == 0) red2[w] = e;
        __syncthreads();
        float lsum = red2[0] + red2[1] + red2[2] + red2[3];

        // weighted V: 16 k-groups x 16 float4 columns (unnormalized)
        int col4 = tid & 15, kg = tid >> 4;
        float ax = 0.f, ay = 0.f, az = 0.f, aw = 0.f;
        for (int j = kg; j < len; j += 16) {
            float sj = sc[j];
            float4 vv = V4[((size_t)bh * LL + k0 + j) * 16 + col4];
            ax += sj * vv.x; ay += sj * vv.y; az += sj * vv.z; aw += sj * vv.w;
        }
        opart[kg][col4][0] = ax;
        opart[kg][col4][1] = ay;
        opart[kg][col4][2] = az;
        opart[kg][col4][3] = aw;
        __syncthreads();
        if (tid < DD) {
            int c4 = tid >> 2, cp = tid & 3;
            float s = 0.f;
            #pragma unroll
            for (int kg2 = 0; kg2 < 16; ++kg2) s += opart[kg2][c4][cp];
            po[pbase * DD + tid] = s;
        }
        if (tid == 0) { pm[pbase] = m; pl[pbase] = lsum; }
    } else {
        if (tid == 0) { pm[pbase] = -INFINITY; pl[pbase] = 0.f; }
        if (tid < DD) po[pbase * DD + tid] = 0.f;
    }

    // last-block combine (canonical threadfence-reduction pattern)
    __threadfence();
    __syncthreads();
    if (tid == 0) {
        int old = atomicAdd(&cnt[g], 1);
        lastFlag = (old == NC - 1);
    }
    __syncthreads();
    if (!lastFlag) return;
    __threadfence();

    if (tid < DD) {
        size_t gb = (size_t)g * NC;
        float gm = -INFINITY;
        #pragma unroll
        for (int j = 0; j < NC; ++j) gm = fmaxf(gm, pm[gb + j]);
        float L = 0.f, o = 0.f;
        #pragma unroll
        for (int j = 0; j < NC; ++j) {
            float wj = expf(pm[gb + j] - gm);
            L += pl[gb + j] * wj;
            o += po[(gb + j) * DD + tid] * wj;
        }
        out[((size_t)bh * LL + qpos) * DD + tid] = o / L;
    }
}

// ---------------------------------------------------------------------------
extern "C" void kernel_launch(void* const* d_in, const int* in_sizes, int n_in,
                              void* d_out, int out_size, void* d_ws, size_t ws_size,
                              hipStream_t stream) {
    const float* Q   = (const float*)d_in[0];
    const float* K   = (const float*)d_in[1];
    const float* V   = (const float*)d_in[2];
    const int*   IDX = (const int*)d_in[3];
    float* out = (float*)d_out;

    char* ws = (char*)d_ws;
    float* M    = (float*)ws;  ws += (size_t)BH * LL * sizeof(float);                 // 256 KB
    int*   topk = (int*)ws;    ws += ((size_t)BH * SK * sizeof(int) + 255) & ~255ull;
    float* csum = (float*)ws;  ws += (size_t)BH * 16 * DD * sizeof(float);            // 128 KB
    int*   cnt  = (int*)ws;    ws += ((size_t)BH * SK * sizeof(int) + 255) & ~255ull;
    float* pm   = (float*)ws;  ws += ((size_t)BH * SK * NC * sizeof(float) + 255) & ~255ull;
    float* pl   = (float*)ws;  ws += ((size_t)BH * SK * NC * sizeof(float) + 255) & ~255ull;
    float* po   = (float*)ws;  // BH*SK*NC*DD floats = 2.62 MB

    stage1_kernel<<<1536, 256, 0, stream>>>(Q, K, V, IDX, M, csum);
    stage2_kernel<<<544, 256, 0, stream>>>(V, csum, M, out, topk, cnt);
    attn_kernel<<<BH * SK * NC, 256, 0, stream>>>(Q, K, V, topk, pm, pl, po, cnt, out);
}

// Round 2
// 168.092 us; speedup vs baseline: 5.9233x; 5.9233x over previous
//
#include <hip/hip_runtime.h>
#include <math.h>

#define BB 4
#define HH 8
#define LL 2048
#define DD 64
#define SK 40            // sample_k == u == 40 for L=2048, FACTOR=5
#define BH (BB*HH)       // 32
#define NC 8             // key-chunks per (bh,u) in attn

__device__ __forceinline__ unsigned ordu(float v) {
    unsigned u = __float_as_uint(v);
    return (u & 0x80000000u) ? ~u : (u | 0x80000000u);
}

// ---------------------------------------------------------------------------
// Stage 1: blocks [0,1024) compute M; blocks [1024,1536) compute V chunk sums.
__global__ __launch_bounds__(256) void stage1_kernel(
        const float* __restrict__ Q, const float* __restrict__ K,
        const float* __restrict__ V, const int* __restrict__ IDX,
        float* __restrict__ M, float* __restrict__ csum) {
    int tid = threadIdx.x;
    if (blockIdx.x < 1024) {
        // ----- compute_M: 4 lanes/query, 16 queries/wave, 64 queries/block
        int x = blockIdx.x;
        int bhLo = x & 7;
        int r = x >> 3;                   // [0,128)
        int bhHi = r & 3;
        int chunk = r >> 2;               // [0,32)
        int bh = bhHi * 8 + bhLo;
        int qbase = chunk * 64;
        int w = tid >> 6, lane = tid & 63;
        int qw = lane >> 2, c = lane & 3;
        int qi = w * 16 + qw;
        int qpos = qbase + qi;

        __shared__ int sidx[64 * SK];     // 10 KB
        for (int i = tid; i < 64 * SK; i += 256) sidx[i] = IDX[(size_t)qbase * SK + i];

        const float4* Q4 = (const float4*)Q;
        const float4* K4 = (const float4*)K;
        float4 qreg[4];
        #pragma unroll
        for (int j = 0; j < 4; ++j)
            qreg[j] = Q4[((size_t)bh * LL + qpos) * 16 + j * 4 + c];
        __syncthreads();

        size_t kb4 = (size_t)bh * LL * 16;
        float mx = -INFINITY, sm = 0.f;
        #pragma unroll 8
        for (int s = 0; s < SK; ++s) {
            int ks = sidx[qi * SK + s];
            const float4* kr = K4 + kb4 + (size_t)ks * 16;
            float p = 0.f;
            #pragma unroll
            for (int j = 0; j < 4; ++j) {
                float4 kv = kr[j * 4 + c];
                p += qreg[j].x * kv.x + qreg[j].y * kv.y + qreg[j].z * kv.z + qreg[j].w * kv.w;
            }
            p += __shfl_xor(p, 1, 64);
            p += __shfl_xor(p, 2, 64);
            mx = fmaxf(mx, p);
            sm += p;
        }
        if (c == 0) M[(size_t)bh * LL + qpos] = mx - sm * (1.0f / (float)LL);
    } else {
        // ----- vsum: per-(bh,chunk-of-128) column sums of V
        int x = blockIdx.x - 1024;        // [0,512)
        int bhLo = x & 7, r = x >> 3;
        int bhHi = r & 3, c = r >> 2;     // c in [0,16)
        int bh = bhHi * 8 + bhLo;
        int d = tid & 63, sg = tid >> 6;
        size_t base = (size_t)bh * LL * DD;
        int row0 = c * 128 + sg * 32;
        float s = 0.f;
        for (int j = 0; j < 32; ++j) s += V[base + (size_t)(row0 + j) * DD + d];
        __shared__ float part[4][DD];
        part[sg][d] = s;
        __syncthreads();
        if (sg == 0)
            csum[((size_t)bh * 16 + c) * DD + d] = part[0][d] + part[1][d] + part[2][d] + part[3][d];
    }
}

// ---------------------------------------------------------------------------
// Stage 2: blocks [0,512) cumsum V -> out; blocks [512,544) radix top-40 of M.
__global__ __launch_bounds__(256) void stage2_kernel(
        const float* __restrict__ V, const float* __restrict__ csum,
        const float* __restrict__ M, float* __restrict__ out,
        int* __restrict__ topk) {
    int tid = threadIdx.x;
    if (blockIdx.x < 512) {
        // ----- cumsum
        int x = blockIdx.x;
        int bhLo = x & 7, r = x >> 3;
        int bhHi = r & 3, c = r >> 2;
        int bh = bhHi * 8 + bhLo;
        int d = tid & 63, sg = tid >> 6;
        size_t base = (size_t)bh * LL * DD;
        int row0 = c * 128 + sg * 32;
        float v[32];
        #pragma unroll
        for (int j = 0; j < 32; ++j) v[j] = V[base + (size_t)(row0 + j) * DD + d];
        float s = 0.f;
        #pragma unroll
        for (int j = 0; j < 32; ++j) s += v[j];
        __shared__ float part[4][DD];
        part[sg][d] = s;
        __syncthreads();
        float pre = 0.f;
        for (int cc = 0; cc < c; ++cc) pre += csum[((size_t)bh * 16 + cc) * DD + d];
        for (int ss = 0; ss < sg; ++ss) pre += part[ss][d];
        float acc = pre;
        #pragma unroll
        for (int j = 0; j < 32; ++j) {
            acc += v[j];
            out[base + (size_t)(row0 + j) * DD + d] = acc;
        }
    } else {
        // ----- radix top-40 (8 bits/pass, 4 passes); unordered emission.
        int bh = blockIdx.x - 512;
        __shared__ unsigned hist[256];
        __shared__ unsigned bc_prefix, bc_need;
        __shared__ unsigned cnt_gt, cnt_eq;
        __shared__ int eqlist[128];

        unsigned v[8];
        #pragma unroll
        for (int j = 0; j < 8; ++j)
            v[j] = ordu(M[(size_t)bh * LL + tid + j * 256]);

        unsigned prefix = 0, need = SK;
        #pragma unroll
        for (int pass = 0; pass < 4; ++pass) {
            const int s = 24 - 8 * pass;
            const unsigned maskHigh = (pass == 0) ? 0u : (0xFFFFFFFFu << (s + 8));
            hist[tid] = 0;
            __syncthreads();
            #pragma unroll
            for (int j = 0; j < 8; ++j)
                if (((v[j] ^ prefix) & maskHigh) == 0)
                    atomicAdd(&hist[(v[j] >> s) & 0xFF], 1u);
            __syncthreads();
            unsigned above = 0;
            for (int b = tid + 1; b < 256; ++b) above += hist[b];
            if (above < need && above + hist[tid] >= need) {
                bc_prefix = prefix | ((unsigned)tid << s);
                bc_need = need - above;
            }
            __syncthreads();
            prefix = bc_prefix;
            need = bc_need;
            __syncthreads();
        }
        unsigned T = prefix;
        if (tid == 0) { cnt_gt = 0; cnt_eq = 0; }
        __syncthreads();
        #pragma unroll
        for (int j = 0; j < 8; ++j) {
            int idx = tid + j * 256;
            if (v[j] > T) { unsigned p = atomicAdd(&cnt_gt, 1u); topk[bh * SK + p] = idx; }
            else if (v[j] == T) { unsigned p = atomicAdd(&cnt_eq, 1u); if (p < 128) eqlist[p] = idx; }
        }
        __syncthreads();
        if (tid == 0) {
            int ne = (int)min(cnt_eq, 128u);
            unsigned base = cnt_gt;       // == SK - need
            for (unsigned r2 = 0; r2 < need; ++r2) {
                int bj = 0, bv = 0x7FFFFFFF;
                for (int j = 0; j < ne; ++j)
                    if (eqlist[j] < bv) { bv = eqlist[j]; bj = j; }
                topk[bh * SK + base + r2] = bv;
                eqlist[bj] = 0x7FFFFFFF;
            }
        }
    }
}

// ---------------------------------------------------------------------------
// Stage 3: flash-style chunked attention. NC chunk-blocks per (bh,u), each
// computes a partial (max, sumexp, weighted-V). NO inter-block communication
// (device-scope fences are catastrophic on non-coherent per-XCD L2s) —
// combine happens in a separate kernel.
__global__ __launch_bounds__(256) void attn_kernel(
        const float* __restrict__ Q, const float* __restrict__ K,
        const float* __restrict__ V, const int* __restrict__ topk,
        float* __restrict__ pm, float* __restrict__ pl,
        float* __restrict__ po) {
    int x = blockIdx.x;               // [0, BH*SK*NC) = 10240
    int bhLo = x & 7;                 // XCD-affinity: same bhLo -> same XCD
    int r = x >> 3;                   // [0, 1280)
    int c = r & 7;                    // chunk index [0,NC)
    r >>= 3;                          // [0, 160)
    int u = r % SK;
    int bhHi = r / SK;                // [0,4)
    int bh = bhHi * 8 + bhLo;
    int g = bh * SK + u;              // group id [0, 1280)
    int tid = threadIdx.x;

    int qpos = topk[g];
    int nk = qpos + 1;
    int cl = (nk + NC - 1) >> 3;      // chunk length (<= 256)
    int k0 = c * cl;
    int len = min(cl, nk - k0);
    if (len <= 0) return;             // combine recomputes chunk validity

    __shared__ float sc[256];
    __shared__ float red[4], red2[4];
    __shared__ float opart[16][16][4];

    size_t pbase = (size_t)g * NC + c;

    int w = tid >> 6, lane = tid & 63;
    int kw = lane >> 2, cc = lane & 3;
    const float4* Q4 = (const float4*)Q;
    const float4* K4 = (const float4*)K;
    const float4* V4 = (const float4*)V;
    float4 qreg[4];
    #pragma unroll
    for (int j = 0; j < 4; ++j)
        qreg[j] = Q4[((size_t)bh * LL + qpos) * 16 + j * 4 + cc];

    // score phase: 4 lanes/key, 64 keys per block-round
    size_t kb4 = (size_t)bh * LL * 16;
    int rounds = (len + 63) >> 6;
    for (int rr = 0; rr < rounds; ++rr) {
        int j = rr * 64 + w * 16 + kw;
        if (j < len) {
            const float4* kr = K4 + kb4 + (size_t)(k0 + j) * 16;
            float p = 0.f;
            #pragma unroll
            for (int jj = 0; jj < 4; ++jj) {
                float4 kv = kr[jj * 4 + cc];
                p += qreg[jj].x * kv.x + qreg[jj].y * kv.y + qreg[jj].z * kv.z + qreg[jj].w * kv.w;
            }
            p += __shfl_xor(p, 1, 64);
            p += __shfl_xor(p, 2, 64);
            if (cc == 0) sc[j] = p * 0.125f;   // 1/sqrt(64)
        }
    }
    __syncthreads();

    // chunk max (len <= 256: one element per thread)
    float m = (tid < len) ? sc[tid] : -INFINITY;
    #pragma unroll
    for (int off = 32; off > 0; off >>= 1) m = fmaxf(m, __shfl_xor(m, off, 64));
    if (lane == 0) red[w] = m;
    __syncthreads();
    m = fmaxf(fmaxf(red[0], red[1]), fmaxf(red[2], red[3]));

    // exp + chunk sum
    float e = 0.f;
    if (tid < len) {
        e = expf(sc[tid] - m);
        sc[tid] = e;
    }
    #pragma unroll
    for (int off = 32; off > 0; off >>= 1) e += __shfl_xor(e, off, 64);
    if (lane == 0) red2[w] = e;
    __syncthreads();
    float lsum = red2[0] + red2[1] + red2[2] + red2[3];

    // weighted V: 16 k-groups x 16 float4 columns (unnormalized)
    int col4 = tid & 15, kg = tid >> 4;
    float ax = 0.f, ay = 0.f, az = 0.f, aw = 0.f;
    for (int j = kg; j < len; j += 16) {
        float sj = sc[j];
        float4 vv = V4[((size_t)bh * LL + k0 + j) * 16 + col4];
        ax += sj * vv.x; ay += sj * vv.y; az += sj * vv.z; aw += sj * vv.w;
    }
    opart[kg][col4][0] = ax;
    opart[kg][col4][1] = ay;
    opart[kg][col4][2] = az;
    opart[kg][col4][3] = aw;
    __syncthreads();
    if (tid < DD) {
        int c4 = tid >> 2, cp = tid & 3;
        float s = 0.f;
        #pragma unroll
        for (int kg2 = 0; kg2 < 16; ++kg2) s += opart[kg2][c4][cp];
        po[pbase * DD + tid] = s;
    }
    if (tid == 0) { pm[pbase] = m; pl[pbase] = lsum; }
}

// ---------------------------------------------------------------------------
// Stage 4: combine partials. One wave per (bh,u) group; 4 groups per block.
__global__ __launch_bounds__(256) void combine_kernel(
        const float* __restrict__ pm, const float* __restrict__ pl,
        const float* __restrict__ po, const int* __restrict__ topk,
        float* __restrict__ out) {
    int g = blockIdx.x * 4 + (threadIdx.x >> 6);   // [0, 1280)
    int d = threadIdx.x & 63;
    int qpos = topk[g];
    int bh = g / SK;
    int nk = qpos + 1;
    int cl = (nk + NC - 1) >> 3;
    int ncv = (nk + cl - 1) / cl;     // number of non-empty chunks
    size_t gb = (size_t)g * NC;
    float gm = -INFINITY;
    for (int j = 0; j < ncv; ++j) gm = fmaxf(gm, pm[gb + j]);
    float L = 0.f, o = 0.f;
    for (int j = 0; j < ncv; ++j) {
        float wj = expf(pm[gb + j] - gm);
        L += pl[gb + j] * wj;
        o += po[(gb + j) * DD + d] * wj;
    }
    out[((size_t)bh * LL + qpos) * DD + d] = o / L;
}

// ---------------------------------------------------------------------------
extern "C" void kernel_launch(void* const* d_in, const int* in_sizes, int n_in,
                              void* d_out, int out_size, void* d_ws, size_t ws_size,
                              hipStream_t stream) {
    const float* Q   = (const float*)d_in[0];
    const float* K   = (const float*)d_in[1];
    const float* V   = (const float*)d_in[2];
    const int*   IDX = (const int*)d_in[3];
    float* out = (float*)d_out;

    char* ws = (char*)d_ws;
    float* M    = (float*)ws;  ws += (size_t)BH * LL * sizeof(float);                 // 256 KB
    int*   topk = (int*)ws;    ws += ((size_t)BH * SK * sizeof(int) + 255) & ~255ull;
    float* csum = (float*)ws;  ws += (size_t)BH * 16 * DD * sizeof(float);            // 128 KB
    float* pm   = (float*)ws;  ws += ((size_t)BH * SK * NC * sizeof(float) + 255) & ~255ull;
    float* pl   = (float*)ws;  ws += ((size_t)BH * SK * NC * sizeof(float) + 255) & ~255ull;
    float* po   = (float*)ws;  // BH*SK*NC*DD floats = 2.62 MB

    stage1_kernel<<<1536, 256, 0, stream>>>(Q, K, V, IDX, M, csum);
    stage2_kernel<<<544, 256, 0, stream>>>(V, csum, M, out, topk);
    attn_kernel<<<BH * SK * NC, 256, 0, stream>>>(Q, K, V, topk, pm, pl, po);
    combine_kernel<<<BH * SK / 4, 256, 0, stream>>>(pm, pl, po, topk, out);
}

// Round 3
// 162.672 us; speedup vs baseline: 6.1207x; 1.0333x over previous
//
#include <hip/hip_runtime.h>
#include <math.h>

#define BB 4
#define HH 8
#define LL 2048
#define DD 64
#define SK 40            // sample_k == u == 40 for L=2048, FACTOR=5
#define BH (BB*HH)       // 32
#define NC 16            // key-chunks per (bh,u) in attn
#define CK 128           // keys per chunk (NC*CK == LL)

__device__ __forceinline__ unsigned ordu(float v) {
    unsigned u = __float_as_uint(v);
    return (u & 0x80000000u) ? ~u : (u | 0x80000000u);
}

// ---------------------------------------------------------------------------
// Stage 1: blocks [0,1024) compute M; blocks [1024,1536) compute V chunk sums.
__global__ __launch_bounds__(256) void stage1_kernel(
        const float* __restrict__ Q, const float* __restrict__ K,
        const float* __restrict__ V, const int* __restrict__ IDX,
        float* __restrict__ M, float* __restrict__ csum) {
    int tid = threadIdx.x;
    if (blockIdx.x < 1024) {
        // ----- compute_M: 4 lanes/query, 16 queries/wave, 64 queries/block
        int x = blockIdx.x;
        int bhLo = x & 7;
        int r = x >> 3;                   // [0,128)
        int bhHi = r & 3;
        int chunk = r >> 2;               // [0,32)
        int bh = bhHi * 8 + bhLo;
        int qbase = chunk * 64;
        int w = tid >> 6, lane = tid & 63;
        int qw = lane >> 2, c = lane & 3;
        int qi = w * 16 + qw;
        int qpos = qbase + qi;

        __shared__ int sidx[64 * SK];     // 10 KB
        for (int i = tid; i < 64 * SK; i += 256) sidx[i] = IDX[(size_t)qbase * SK + i];

        const float4* Q4 = (const float4*)Q;
        const float4* K4 = (const float4*)K;
        float4 qreg[4];
        #pragma unroll
        for (int j = 0; j < 4; ++j)
            qreg[j] = Q4[((size_t)bh * LL + qpos) * 16 + j * 4 + c];
        __syncthreads();

        size_t kb4 = (size_t)bh * LL * 16;
        float mx = -INFINITY, sm = 0.f;
        // 4-sample batches: 16 float4 loads in flight per lane (real MLP).
        #pragma unroll
        for (int s0 = 0; s0 < SK; s0 += 4) {
            float4 kv[4][4];
            #pragma unroll
            for (int t = 0; t < 4; ++t) {
                int ks = sidx[qi * SK + s0 + t];
                const float4* kr = K4 + kb4 + (size_t)ks * 16;
                #pragma unroll
                for (int j = 0; j < 4; ++j) kv[t][j] = kr[j * 4 + c];
            }
            #pragma unroll
            for (int t = 0; t < 4; ++t) {
                float p = 0.f;
                #pragma unroll
                for (int j = 0; j < 4; ++j)
                    p += qreg[j].x * kv[t][j].x + qreg[j].y * kv[t][j].y
                       + qreg[j].z * kv[t][j].z + qreg[j].w * kv[t][j].w;
                p += __shfl_xor(p, 1, 64);
                p += __shfl_xor(p, 2, 64);
                mx = fmaxf(mx, p);
                sm += p;
            }
        }
        if (c == 0) M[(size_t)bh * LL + qpos] = mx - sm * (1.0f / (float)LL);
    } else {
        // ----- vsum: per-(bh,chunk-of-128) column sums of V
        int x = blockIdx.x - 1024;        // [0,512)
        int bhLo = x & 7, r = x >> 3;
        int bhHi = r & 3, c = r >> 2;     // c in [0,16)
        int bh = bhHi * 8 + bhLo;
        int d = tid & 63, sg = tid >> 6;
        size_t base = (size_t)bh * LL * DD;
        int row0 = c * 128 + sg * 32;
        float s = 0.f;
        for (int j = 0; j < 32; ++j) s += V[base + (size_t)(row0 + j) * DD + d];
        __shared__ float part[4][DD];
        part[sg][d] = s;
        __syncthreads();
        if (sg == 0)
            csum[((size_t)bh * 16 + c) * DD + d] = part[0][d] + part[1][d] + part[2][d] + part[3][d];
    }
}

// ---------------------------------------------------------------------------
// Stage 2: blocks [0,512) cumsum V -> out; blocks [512,544) radix top-40 of M.
__global__ __launch_bounds__(256) void stage2_kernel(
        const float* __restrict__ V, const float* __restrict__ csum,
        const float* __restrict__ M, float* __restrict__ out,
        int* __restrict__ topk) {
    int tid = threadIdx.x;
    if (blockIdx.x < 512) {
        // ----- cumsum
        int x = blockIdx.x;
        int bhLo = x & 7, r = x >> 3;
        int bhHi = r & 3, c = r >> 2;
        int bh = bhHi * 8 + bhLo;
        int d = tid & 63, sg = tid >> 6;
        size_t base = (size_t)bh * LL * DD;
        int row0 = c * 128 + sg * 32;
        float v[32];
        #pragma unroll
        for (int j = 0; j < 32; ++j) v[j] = V[base + (size_t)(row0 + j) * DD + d];
        float s = 0.f;
        #pragma unroll
        for (int j = 0; j < 32; ++j) s += v[j];
        __shared__ float part[4][DD];
        part[sg][d] = s;
        __syncthreads();
        float pre = 0.f;
        for (int cc = 0; cc < c; ++cc) pre += csum[((size_t)bh * 16 + cc) * DD + d];
        for (int ss = 0; ss < sg; ++ss) pre += part[ss][d];
        float acc = pre;
        #pragma unroll
        for (int j = 0; j < 32; ++j) {
            acc += v[j];
            out[base + (size_t)(row0 + j) * DD + d] = acc;
        }
    } else {
        // ----- radix top-40 (8 bits/pass, 4 passes); unordered emission.
        int bh = blockIdx.x - 512;
        __shared__ unsigned hist[256];
        __shared__ unsigned bc_prefix, bc_need;
        __shared__ unsigned cnt_gt, cnt_eq;
        __shared__ int eqlist[128];

        unsigned v[8];
        #pragma unroll
        for (int j = 0; j < 8; ++j)
            v[j] = ordu(M[(size_t)bh * LL + tid + j * 256]);

        unsigned prefix = 0, need = SK;
        #pragma unroll
        for (int pass = 0; pass < 4; ++pass) {
            const int s = 24 - 8 * pass;
            const unsigned maskHigh = (pass == 0) ? 0u : (0xFFFFFFFFu << (s + 8));
            hist[tid] = 0;
            __syncthreads();
            #pragma unroll
            for (int j = 0; j < 8; ++j)
                if (((v[j] ^ prefix) & maskHigh) == 0)
                    atomicAdd(&hist[(v[j] >> s) & 0xFF], 1u);
            __syncthreads();
            unsigned above = 0;
            for (int b = tid + 1; b < 256; ++b) above += hist[b];
            if (above < need && above + hist[tid] >= need) {
                bc_prefix = prefix | ((unsigned)tid << s);
                bc_need = need - above;
            }
            __syncthreads();
            prefix = bc_prefix;
            need = bc_need;
            __syncthreads();
        }
        unsigned T = prefix;
        if (tid == 0) { cnt_gt = 0; cnt_eq = 0; }
        __syncthreads();
        #pragma unroll
        for (int j = 0; j < 8; ++j) {
            int idx = tid + j * 256;
            if (v[j] > T) { unsigned p = atomicAdd(&cnt_gt, 1u); topk[bh * SK + p] = idx; }
            else if (v[j] == T) { unsigned p = atomicAdd(&cnt_eq, 1u); if (p < 128) eqlist[p] = idx; }
        }
        __syncthreads();
        if (tid == 0) {
            int ne = (int)min(cnt_eq, 128u);
            unsigned base = cnt_gt;       // == SK - need
            for (unsigned r2 = 0; r2 < need; ++r2) {
                int bj = 0, bv = 0x7FFFFFFF;
                for (int j = 0; j < ne; ++j)
                    if (eqlist[j] < bv) { bv = eqlist[j]; bj = j; }
                topk[bh * SK + base + r2] = bv;
                eqlist[bj] = 0x7FFFFFFF;
            }
        }
    }
}

// ---------------------------------------------------------------------------
// Stage 3: one block per (bh, key-chunk of CK). Stages all 40 Q rows in LDS,
// computes scores for all 40 u's vs the chunk (K/V read ONCE per bh), writes
// per-(u,chunk) partials (m, sumexp, weighted-V). Fully-masked chunks emit
// pm=-inf/pl=0/po=0. Combine kernel merges.
__global__ __launch_bounds__(256) void attn_kernel(
        const float* __restrict__ Q, const float* __restrict__ K,
        const float* __restrict__ V, const int* __restrict__ topk,
        float* __restrict__ pm, float* __restrict__ pl,
        float* __restrict__ po) {
    int x = blockIdx.x;               // [0, 512)
    int bhLo = x & 7;                 // XCD affinity: 4 bh per XCD -> 4MB K/V in L2
    int r = x >> 3;                   // [0,64)
    int c = r & 15;                   // chunk [0,NC)
    int bhHi = r >> 4;                // [0,4)
    int bh = bhHi * 8 + bhLo;
    int tid = threadIdx.x;
    int w = tid >> 6, lane = tid & 63;
    int cbase = c * CK;

    __shared__ int qp[SK];
    __shared__ float4 sq4[SK][16];     // 10 KB: 40 Q rows
    __shared__ float SC[CK][SK + 1];   // 21 KB, pad 41 -> conflict-free

    if (tid < SK) qp[tid] = topk[bh * SK + tid];
    __syncthreads();
    const float4* Q4 = (const float4*)Q;
    const float4* K4 = (const float4*)K;
    const float4* V4 = (const float4*)V;
    for (int i = tid; i < SK * 16; i += 256) {
        int u = i >> 4, j = i & 15;
        sq4[u][j] = Q4[((size_t)bh * LL + qp[u]) * 16 + j];
    }
    __syncthreads();

    // ---- Phase A: scores. thread = (key kk, half of D); K half-row in regs.
    {
        int half = tid & 1;
        int kk = tid >> 1;            // [0,128)
        int kg = cbase + kk;          // global key index
        size_t kb4 = (size_t)bh * LL * 16;
        float4 kreg[8];
        const float4* kr = K4 + kb4 + (size_t)kg * 16 + half * 8;
        #pragma unroll
        for (int j = 0; j < 8; ++j) kreg[j] = kr[j];
        #pragma unroll 4
        for (int u = 0; u < SK; ++u) {
            int qpu = qp[u];
            if (cbase > qpu) {        // chunk fully masked for this u (uniform)
                if (half == 0) SC[kk][u] = -INFINITY;
                continue;
            }
            float pa = 0.f, pb = 0.f;
            #pragma unroll
            for (int j = 0; j < 4; ++j) {
                float4 qv = sq4[u][half * 8 + j];
                pa += kreg[j].x * qv.x + kreg[j].y * qv.y + kreg[j].z * qv.z + kreg[j].w * qv.w;
            }
            #pragma unroll
            for (int j = 4; j < 8; ++j) {
                float4 qv = sq4[u][half * 8 + j];
                pb += kreg[j].x * qv.x + kreg[j].y * qv.y + kreg[j].z * qv.z + kreg[j].w * qv.w;
            }
            float p = pa + pb;
            p += __shfl_xor(p, 1, 64);   // combine the two halves
            if (half == 0) SC[kk][u] = (kg <= qpu) ? p * 0.125f : -INFINITY;
        }
    }
    __syncthreads();

    // ---- Phase B: per-u chunk max + exp + sumexp (wave w handles u = w,w+4,...)
    for (int u = w; u < SK; u += 4) {
        float s0 = SC[lane][u], s1 = SC[lane + 64][u];
        float m = fmaxf(s0, s1);
        #pragma unroll
        for (int off = 32; off > 0; off >>= 1) m = fmaxf(m, __shfl_xor(m, off, 64));
        float e0 = 0.f, e1 = 0.f;
        if (m != -INFINITY) {
            e0 = expf(s0 - m);           // s==-inf -> 0
            e1 = expf(s1 - m);
        }
        SC[lane][u] = e0;
        SC[lane + 64][u] = e1;
        float ls = e0 + e1;
        #pragma unroll
        for (int off = 32; off > 0; off >>= 1) ls += __shfl_xor(ls, off, 64);
        if (lane == 0) {
            size_t pb = (size_t)(bh * SK + u) * NC + c;
            pm[pb] = m;
            pl[pb] = ls;
        }
    }
    __syncthreads();

    // ---- Phase C: PV = P(40xCK) x V(CKx64). thread = (ks, dg, ug):
    // 10 u x 4 d tile per thread, k-split 4 ways, shfl-combine.
    {
        int ks = tid & 3;
        int dg = (tid >> 2) & 15;
        int ug = tid >> 6;            // == w
        int u0 = ug * 10;
        float4 acc[10];
        #pragma unroll
        for (int i = 0; i < 10; ++i) acc[i] = make_float4(0.f, 0.f, 0.f, 0.f);
        for (int t = 0; t < CK / 4; ++t) {
            int k = t * 4 + ks;
            float4 vv = V4[((size_t)bh * LL + cbase + k) * 16 + dg];
            #pragma unroll
            for (int i = 0; i < 10; ++i) {
                float pw = SC[k][u0 + i];
                acc[i].x += pw * vv.x; acc[i].y += pw * vv.y;
                acc[i].z += pw * vv.z; acc[i].w += pw * vv.w;
            }
        }
        #pragma unroll
        for (int i = 0; i < 10; ++i) {
            acc[i].x += __shfl_xor(acc[i].x, 1, 64); acc[i].x += __shfl_xor(acc[i].x, 2, 64);
            acc[i].y += __shfl_xor(acc[i].y, 1, 64); acc[i].y += __shfl_xor(acc[i].y, 2, 64);
            acc[i].z += __shfl_xor(acc[i].z, 1, 64); acc[i].z += __shfl_xor(acc[i].z, 2, 64);
            acc[i].w += __shfl_xor(acc[i].w, 1, 64); acc[i].w += __shfl_xor(acc[i].w, 2, 64);
        }
        if (ks == 0) {
            #pragma unroll
            for (int i = 0; i < 10; ++i) {
                float4* dst = (float4*)&po[((size_t)(bh * SK + u0 + i) * NC + c) * DD + dg * 4];
                *dst = acc[i];
            }
        }
    }
}

// ---------------------------------------------------------------------------
// Stage 4: combine partials. One wave per (bh,u) group; 4 groups per block.
__global__ __launch_bounds__(256) void combine_kernel(
        const float* __restrict__ pm, const float* __restrict__ pl,
        const float* __restrict__ po, const int* __restrict__ topk,
        float* __restrict__ out) {
    int g = blockIdx.x * 4 + (threadIdx.x >> 6);   // [0, 1280)
    int d = threadIdx.x & 63;
    int qpos = topk[g];
    int bh = g / SK;
    size_t gb = (size_t)g * NC;
    float gm = -INFINITY;
    #pragma unroll
    for (int j = 0; j < NC; ++j) gm = fmaxf(gm, pm[gb + j]);
    float L = 0.f, o = 0.f;
    #pragma unroll
    for (int j = 0; j < NC; ++j) {
        float pmj = pm[gb + j];
        float wj = (pmj == -INFINITY) ? 0.f : expf(pmj - gm);
        L += pl[gb + j] * wj;
        o += po[(gb + j) * DD + d] * wj;
    }
    out[((size_t)bh * LL + qpos) * DD + d] = o / L;
}

// ---------------------------------------------------------------------------
extern "C" void kernel_launch(void* const* d_in, const int* in_sizes, int n_in,
                              void* d_out, int out_size, void* d_ws, size_t ws_size,
                              hipStream_t stream) {
    const float* Q   = (const float*)d_in[0];
    const float* K   = (const float*)d_in[1];
    const float* V   = (const float*)d_in[2];
    const int*   IDX = (const int*)d_in[3];
    float* out = (float*)d_out;

    char* ws = (char*)d_ws;
    float* M    = (float*)ws;  ws += (size_t)BH * LL * sizeof(float);                 // 256 KB
    int*   topk = (int*)ws;    ws += ((size_t)BH * SK * sizeof(int) + 255) & ~255ull;
    float* csum = (float*)ws;  ws += (size_t)BH * 16 * DD * sizeof(float);            // 128 KB
    float* pm   = (float*)ws;  ws += ((size_t)BH * SK * NC * sizeof(float) + 255) & ~255ull;
    float* pl   = (float*)ws;  ws += ((size_t)BH * SK * NC * sizeof(float) + 255) & ~255ull;
    float* po   = (float*)ws;  // BH*SK*NC*DD floats = 5.24 MB

    stage1_kernel<<<1536, 256, 0, stream>>>(Q, K, V, IDX, M, csum);
    stage2_kernel<<<544, 256, 0, stream>>>(V, csum, M, out, topk);
    attn_kernel<<<BH * NC, 256, 0, stream>>>(Q, K, V, topk, pm, pl, po);
    combine_kernel<<<BH * SK / 4, 256, 0, stream>>>(pm, pl, po, topk, out);
}

// Round 4
// 160.822 us; speedup vs baseline: 6.1911x; 1.0115x over previous
//
#include <hip/hip_runtime.h>
#include <math.h>

#define BB 4
#define HH 8
#define LL 2048
#define DD 64
#define SK 40            // sample_k == u == 40 for L=2048, FACTOR=5
#define BH (BB*HH)       // 32
#define NC 16            // key-chunks per (bh,u) in attn
#define CK 128           // keys per chunk (NC*CK == LL)

__device__ __forceinline__ unsigned ordu(float v) {
    unsigned u = __float_as_uint(v);
    return (u & 0x80000000u) ? ~u : (u | 0x80000000u);
}

__device__ __forceinline__ float dot4(float4 a, float4 b) {
    return a.x * b.x + a.y * b.y + a.z * b.z + a.w * b.w;
}

// ---------------------------------------------------------------------------
// Stage 1: blocks [0,2048) compute M (32 queries/block, 8 lanes/query);
//          blocks [2048,2560) compute V chunk sums.
__global__ __launch_bounds__(256) void stage1_kernel(
        const float* __restrict__ Q, const float* __restrict__ K,
        const float* __restrict__ V, const int* __restrict__ IDX,
        float* __restrict__ M, float* __restrict__ csum) {
    int tid = threadIdx.x;
    if (blockIdx.x < 2048) {
        // ----- compute_M: 8 lanes/query, 8 queries/wave, 32 queries/block.
        // Max resident concurrency: 2048 blocks = 8/CU, VGPR ~60 -> 8 waves/SIMD.
        int x = blockIdx.x;
        int bhLo = x & 7;
        int r = x >> 3;                   // [0,256)
        int bhHi = r & 3;
        int chunk = r >> 2;               // [0,64)
        int bh = bhHi * 8 + bhLo;
        int qbase = chunk * 32;
        int w = tid >> 6, lane = tid & 63;
        int q8 = lane >> 3, c8 = lane & 7;
        int qi = w * 8 + q8;              // [0,32)
        int qpos = qbase + qi;
        int qi41 = qi * 41;

        __shared__ int sidx[32 * 41];     // padded stride 41: conflict-free broadcast
        for (int i = tid; i < 32 * SK; i += 256)
            sidx[(i / SK) * 41 + (i % SK)] = IDX[(size_t)qbase * SK + i];

        const float4* Q4 = (const float4*)Q;
        const float4* K4 = (const float4*)K;
        float4 qreg[2];
        qreg[0] = Q4[((size_t)bh * LL + qpos) * 16 + c8];
        qreg[1] = Q4[((size_t)bh * LL + qpos) * 16 + c8 + 8];
        __syncthreads();

        size_t kb4 = (size_t)bh * LL * 16;
        float mx = -INFINITY, sm = 0.f;
        // 4-sample batches: 8 float4 loads in flight per lane at modest VGPR.
        #pragma unroll
        for (int s0 = 0; s0 < SK; s0 += 4) {
            float4 kv[4][2];
            #pragma unroll
            for (int t = 0; t < 4; ++t) {
                int ks = sidx[qi41 + s0 + t];
                const float4* kr = K4 + kb4 + (size_t)ks * 16;
                kv[t][0] = kr[c8];
                kv[t][1] = kr[c8 + 8];
            }
            #pragma unroll
            for (int t = 0; t < 4; ++t) {
                float p = dot4(qreg[0], kv[t][0]) + dot4(qreg[1], kv[t][1]);
                p += __shfl_xor(p, 1, 64);
                p += __shfl_xor(p, 2, 64);
                p += __shfl_xor(p, 4, 64);
                mx = fmaxf(mx, p);
                sm += p;
            }
        }
        if (c8 == 0) M[(size_t)bh * LL + qpos] = mx - sm * (1.0f / (float)LL);
    } else {
        // ----- vsum: per-(bh,chunk-of-128) column sums of V
        int x = blockIdx.x - 2048;        // [0,512)
        int bhLo = x & 7, r = x >> 3;
        int bhHi = r & 3, c = r >> 2;     // c in [0,16)
        int bh = bhHi * 8 + bhLo;
        int d = tid & 63, sg = tid >> 6;
        size_t base = (size_t)bh * LL * DD;
        int row0 = c * 128 + sg * 32;
        float s = 0.f;
        for (int j = 0; j < 32; ++j) s += V[base + (size_t)(row0 + j) * DD + d];
        __shared__ float part[4][DD];
        part[sg][d] = s;
        __syncthreads();
        if (sg == 0)
            csum[((size_t)bh * 16 + c) * DD + d] = part[0][d] + part[1][d] + part[2][d] + part[3][d];
    }
}

// ---------------------------------------------------------------------------
// Stage 2: blocks [0,512) cumsum V -> out; blocks [512,544) radix top-40 of M.
__global__ __launch_bounds__(256) void stage2_kernel(
        const float* __restrict__ V, const float* __restrict__ csum,
        const float* __restrict__ M, float* __restrict__ out,
        int* __restrict__ topk) {
    int tid = threadIdx.x;
    if (blockIdx.x < 512) {
        // ----- cumsum
        int x = blockIdx.x;
        int bhLo = x & 7, r = x >> 3;
        int bhHi = r & 3, c = r >> 2;
        int bh = bhHi * 8 + bhLo;
        int d = tid & 63, sg = tid >> 6;
        size_t base = (size_t)bh * LL * DD;
        int row0 = c * 128 + sg * 32;
        float v[32];
        #pragma unroll
        for (int j = 0; j < 32; ++j) v[j] = V[base + (size_t)(row0 + j) * DD + d];
        float s = 0.f;
        #pragma unroll
        for (int j = 0; j < 32; ++j) s += v[j];
        __shared__ float part[4][DD];
        part[sg][d] = s;
        __syncthreads();
        float pre = 0.f;
        for (int cc = 0; cc < c; ++cc) pre += csum[((size_t)bh * 16 + cc) * DD + d];
        for (int ss = 0; ss < sg; ++ss) pre += part[ss][d];
        float acc = pre;
        #pragma unroll
        for (int j = 0; j < 32; ++j) {
            acc += v[j];
            out[base + (size_t)(row0 + j) * DD + d] = acc;
        }
    } else {
        // ----- radix top-40 (8 bits/pass, 4 passes); unordered emission.
        int bh = blockIdx.x - 512;
        __shared__ unsigned hist[256];
        __shared__ unsigned bc_prefix, bc_need;
        __shared__ unsigned cnt_gt, cnt_eq;
        __shared__ int eqlist[128];

        unsigned v[8];
        #pragma unroll
        for (int j = 0; j < 8; ++j)
            v[j] = ordu(M[(size_t)bh * LL + tid + j * 256]);

        unsigned prefix = 0, need = SK;
        #pragma unroll
        for (int pass = 0; pass < 4; ++pass) {
            const int s = 24 - 8 * pass;
            const unsigned maskHigh = (pass == 0) ? 0u : (0xFFFFFFFFu << (s + 8));
            hist[tid] = 0;
            __syncthreads();
            #pragma unroll
            for (int j = 0; j < 8; ++j)
                if (((v[j] ^ prefix) & maskHigh) == 0)
                    atomicAdd(&hist[(v[j] >> s) & 0xFF], 1u);
            __syncthreads();
            unsigned above = 0;
            for (int b = tid + 1; b < 256; ++b) above += hist[b];
            if (above < need && above + hist[tid] >= need) {
                bc_prefix = prefix | ((unsigned)tid << s);
                bc_need = need - above;
            }
            __syncthreads();
            prefix = bc_prefix;
            need = bc_need;
            __syncthreads();
        }
        unsigned T = prefix;
        if (tid == 0) { cnt_gt = 0; cnt_eq = 0; }
        __syncthreads();
        #pragma unroll
        for (int j = 0; j < 8; ++j) {
            int idx = tid + j * 256;
            if (v[j] > T) { unsigned p = atomicAdd(&cnt_gt, 1u); topk[bh * SK + p] = idx; }
            else if (v[j] == T) { unsigned p = atomicAdd(&cnt_eq, 1u); if (p < 128) eqlist[p] = idx; }
        }
        __syncthreads();
        if (tid == 0) {
            int ne = (int)min(cnt_eq, 128u);
            unsigned base = cnt_gt;       // == SK - need
            for (unsigned r2 = 0; r2 < need; ++r2) {
                int bj = 0, bv = 0x7FFFFFFF;
                for (int j = 0; j < ne; ++j)
                    if (eqlist[j] < bv) { bv = eqlist[j]; bj = j; }
                topk[bh * SK + base + r2] = bv;
                eqlist[bj] = 0x7FFFFFFF;
            }
        }
    }
}

// ---------------------------------------------------------------------------
// Stage 3: one block per (bh, key-chunk of CK). Stages all 40 Q rows in LDS,
// computes scores for all 40 u's vs the chunk (K/V read ONCE per bh), writes
// per-(u,chunk) partials (m, sumexp, weighted-V). Fully-masked chunks emit
// pm=-inf/pl=0/po=0. Combine kernel merges.
__global__ __launch_bounds__(256) void attn_kernel(
        const float* __restrict__ Q, const float* __restrict__ K,
        const float* __restrict__ V, const int* __restrict__ topk,
        float* __restrict__ pm, float* __restrict__ pl,
        float* __restrict__ po) {
    int x = blockIdx.x;               // [0, 512)
    int bhLo = x & 7;                 // XCD affinity: 4 bh per XCD -> 4MB K/V in L2
    int r = x >> 3;                   // [0,64)
    int c = r & 15;                   // chunk [0,NC)
    int bhHi = r >> 4;                // [0,4)
    int bh = bhHi * 8 + bhLo;
    int tid = threadIdx.x;
    int w = tid >> 6, lane = tid & 63;
    int cbase = c * CK;

    __shared__ int qp[SK];
    __shared__ float4 sq4[SK][16];     // 10 KB: 40 Q rows
    __shared__ float SC[CK][SK + 1];   // 21 KB, pad 41 -> conflict-free

    if (tid < SK) qp[tid] = topk[bh * SK + tid];
    __syncthreads();
    const float4* Q4 = (const float4*)Q;
    const float4* K4 = (const float4*)K;
    const float4* V4 = (const float4*)V;
    for (int i = tid; i < SK * 16; i += 256) {
        int u = i >> 4, j = i & 15;
        sq4[u][j] = Q4[((size_t)bh * LL + qp[u]) * 16 + j];
    }
    __syncthreads();

    // ---- Phase A: scores. thread = (key kk, half of D); K half-row in regs.
    {
        int half = tid & 1;
        int kk = tid >> 1;            // [0,128)
        int kg = cbase + kk;          // global key index
        size_t kb4 = (size_t)bh * LL * 16;
        float4 kreg[8];
        const float4* kr = K4 + kb4 + (size_t)kg * 16 + half * 8;
        #pragma unroll
        for (int j = 0; j < 8; ++j) kreg[j] = kr[j];
        #pragma unroll 4
        for (int u = 0; u < SK; ++u) {
            int qpu = qp[u];
            if (cbase > qpu) {        // chunk fully masked for this u (uniform)
                if (half == 0) SC[kk][u] = -INFINITY;
                continue;
            }
            float pa = 0.f, pb = 0.f;
            #pragma unroll
            for (int j = 0; j < 4; ++j) {
                float4 qv = sq4[u][half * 8 + j];
                pa += kreg[j].x * qv.x + kreg[j].y * qv.y + kreg[j].z * qv.z + kreg[j].w * qv.w;
            }
            #pragma unroll
            for (int j = 4; j < 8; ++j) {
                float4 qv = sq4[u][half * 8 + j];
                pb += kreg[j].x * qv.x + kreg[j].y * qv.y + kreg[j].z * qv.z + kreg[j].w * qv.w;
            }
            float p = pa + pb;
            p += __shfl_xor(p, 1, 64);   // combine the two halves
            if (half == 0) SC[kk][u] = (kg <= qpu) ? p * 0.125f : -INFINITY;
        }
    }
    __syncthreads();

    // ---- Phase B: per-u chunk max + exp + sumexp (wave w handles u = w,w+4,...)
    for (int u = w; u < SK; u += 4) {
        float s0 = SC[lane][u], s1 = SC[lane + 64][u];
        float m = fmaxf(s0, s1);
        #pragma unroll
        for (int off = 32; off > 0; off >>= 1) m = fmaxf(m, __shfl_xor(m, off, 64));
        float e0 = 0.f, e1 = 0.f;
        if (m != -INFINITY) {
            e0 = expf(s0 - m);           // s==-inf -> 0
            e1 = expf(s1 - m);
        }
        SC[lane][u] = e0;
        SC[lane + 64][u] = e1;
        float ls = e0 + e1;
        #pragma unroll
        for (int off = 32; off > 0; off >>= 1) ls += __shfl_xor(ls, off, 64);
        if (lane == 0) {
            size_t pb = (size_t)(bh * SK + u) * NC + c;
            pm[pb] = m;
            pl[pb] = ls;
        }
    }
    __syncthreads();

    // ---- Phase C: PV = P(40xCK) x V(CKx64). thread = (ks, dg, ug):
    // 10 u x 4 d tile per thread, k-split 4 ways, shfl-combine.
    {
        int ks = tid & 3;
        int dg = (tid >> 2) & 15;
        int ug = tid >> 6;            // == w
        int u0 = ug * 10;
        float4 acc[10];
        #pragma unroll
        for (int i = 0; i < 10; ++i) acc[i] = make_float4(0.f, 0.f, 0.f, 0.f);
        for (int t = 0; t < CK / 4; ++t) {
            int k = t * 4 + ks;
            float4 vv = V4[((size_t)bh * LL + cbase + k) * 16 + dg];
            #pragma unroll
            for (int i = 0; i < 10; ++i) {
                float pw = SC[k][u0 + i];
                acc[i].x += pw * vv.x; acc[i].y += pw * vv.y;
                acc[i].z += pw * vv.z; acc[i].w += pw * vv.w;
            }
        }
        #pragma unroll
        for (int i = 0; i < 10; ++i) {
            acc[i].x += __shfl_xor(acc[i].x, 1, 64); acc[i].x += __shfl_xor(acc[i].x, 2, 64);
            acc[i].y += __shfl_xor(acc[i].y, 1, 64); acc[i].y += __shfl_xor(acc[i].y, 2, 64);
            acc[i].z += __shfl_xor(acc[i].z, 1, 64); acc[i].z += __shfl_xor(acc[i].z, 2, 64);
            acc[i].w += __shfl_xor(acc[i].w, 1, 64); acc[i].w += __shfl_xor(acc[i].w, 2, 64);
        }
        if (ks == 0) {
            #pragma unroll
            for (int i = 0; i < 10; ++i) {
                float4* dst = (float4*)&po[((size_t)(bh * SK + u0 + i) * NC + c) * DD + dg * 4];
                *dst = acc[i];
            }
        }
    }
}

// ---------------------------------------------------------------------------
// Stage 4: combine partials. One wave per (bh,u) group; 4 groups per block.
__global__ __launch_bounds__(256) void combine_kernel(
        const float* __restrict__ pm, const float* __restrict__ pl,
        const float* __restrict__ po, const int* __restrict__ topk,
        float* __restrict__ out) {
    int g = blockIdx.x * 4 + (threadIdx.x >> 6);   // [0, 1280)
    int d = threadIdx.x & 63;
    int qpos = topk[g];
    int bh = g / SK;
    size_t gb = (size_t)g * NC;
    float gm = -INFINITY;
    #pragma unroll
    for (int j = 0; j < NC; ++j) gm = fmaxf(gm, pm[gb + j]);
    float L = 0.f, o = 0.f;
    #pragma unroll
    for (int j = 0; j < NC; ++j) {
        float pmj = pm[gb + j];
        float wj = (pmj == -INFINITY) ? 0.f : expf(pmj - gm);
        L += pl[gb + j] * wj;
        o += po[(gb + j) * DD + d] * wj;
    }
    out[((size_t)bh * LL + qpos) * DD + d] = o / L;
}

// ---------------------------------------------------------------------------
extern "C" void kernel_launch(void* const* d_in, const int* in_sizes, int n_in,
                              void* d_out, int out_size, void* d_ws, size_t ws_size,
                              hipStream_t stream) {
    const float* Q   = (const float*)d_in[0];
    const float* K   = (const float*)d_in[1];
    const float* V   = (const float*)d_in[2];
    const int*   IDX = (const int*)d_in[3];
    float* out = (float*)d_out;

    char* ws = (char*)d_ws;
    float* M    = (float*)ws;  ws += (size_t)BH * LL * sizeof(float);                 // 256 KB
    int*   topk = (int*)ws;    ws += ((size_t)BH * SK * sizeof(int) + 255) & ~255ull;
    float* csum = (float*)ws;  ws += (size_t)BH * 16 * DD * sizeof(float);            // 128 KB
    float* pm   = (float*)ws;  ws += ((size_t)BH * SK * NC * sizeof(float) + 255) & ~255ull;
    float* pl   = (float*)ws;  ws += ((size_t)BH * SK * NC * sizeof(float) + 255) & ~255ull;
    float* po   = (float*)ws;  // BH*SK*NC*DD floats = 5.24 MB

    stage1_kernel<<<2560, 256, 0, stream>>>(Q, K, V, IDX, M, csum);
    stage2_kernel<<<544, 256, 0, stream>>>(V, csum, M, out, topk);
    attn_kernel<<<BH * NC, 256, 0, stream>>>(Q, K, V, topk, pm, pl, po);
    combine_kernel<<<BH * SK / 4, 256, 0, stream>>>(pm, pl, po, topk, out);
}